// Round 8
// baseline (215.066 us; speedup 1.0000x reference)
//
#include <hip/hip_runtime.h>
#include <hip/hip_bf16.h>
#include <math.h>

typedef __bf16 bf16x8 __attribute__((ext_vector_type(8)));
typedef __bf16 bf16x4 __attribute__((ext_vector_type(4)));
typedef float  f32x4  __attribute__((ext_vector_type(4)));

constexpr int EMBED = 1024;
constexpr int NH    = 16;
constexpr int HD    = 64;
constexpr int LL    = 2048;
constexpr int BB    = 2;
constexpr int SSEQ  = 2048;

constexpr int BQ = 128;         // q rows per block (8 waves x 16)
constexpr int BK = 64;          // kv rows per tile
constexpr int NT = SSEQ / BK;   // 32 tiles

// Workspace: K bf16 [b][h][s][d] (8 MiB) then V^T bf16 [b][h][d][s] (8 MiB)
constexpr size_t KW_ELEMS = (size_t)BB * NH * SSEQ * HD;

__device__ __forceinline__ void gload16(const void* g, void* l) {
  __builtin_amdgcn_global_load_lds((const __attribute__((address_space(1))) unsigned int*)g,
                                   (__attribute__((address_space(3))) unsigned int*)l, 16, 0, 0);
}

__device__ __forceinline__ float exp2_fast(float x) {
  float r;
  asm("v_exp_f32 %0, %1" : "=v"(r) : "v"(x));
  return r;
}

// ---- prepass: K -> bf16 [b][h][s][d]; V -> bf16 transposed [b][h][d][s] ----
__global__ __launch_bounds__(256) void prep_kv(const float* __restrict__ Kg,
                                               const float* __restrict__ Vg,
                                               __hip_bfloat16* __restrict__ kw,
                                               __hip_bfloat16* __restrict__ vtw) {
  __shared__ char tsh[64 * 128];
  const int bid = blockIdx.x;
  if (bid < 2048) {
    const int idx = bid * 256 + threadIdx.x;
    const int e8 = idx & 127;
    const int t2 = idx >> 7;
    const int b  = t2 & 1;
    const int s  = t2 >> 1;
    const int h  = e8 >> 3;
    const int d8 = e8 & 7;
    const float* src = Kg + ((size_t)s * BB + b) * EMBED + e8 * 8;
    float4 a = *(const float4*)src;
    float4 c = *(const float4*)(src + 4);
    bf16x8 w;
    w[0] = (__bf16)a.x; w[1] = (__bf16)a.y; w[2] = (__bf16)a.z; w[3] = (__bf16)a.w;
    w[4] = (__bf16)c.x; w[5] = (__bf16)c.y; w[6] = (__bf16)c.z; w[7] = (__bf16)c.w;
    *(bf16x8*)(kw + (((size_t)(b * NH + h) * SSEQ + s) * HD + d8 * 8)) = w;
  } else {
    const int vb2 = bid - 2048;
    const int st  = vb2 & 31;
    const int bh  = vb2 >> 5;
    const int b   = bh >> 4;
    const int h   = bh & 15;
    const int t   = threadIdx.x;
    {
      const int r  = t >> 2;
      const int c0 = (t & 3) * 16;
      const float* src = Vg + ((size_t)(st * 64 + r) * BB + b) * EMBED + h * HD + c0;
      float4 x0 = *(const float4*)(src);
      float4 x1 = *(const float4*)(src + 4);
      float4 x2 = *(const float4*)(src + 8);
      float4 x3 = *(const float4*)(src + 12);
      bf16x8 w0, w1;
      w0[0] = (__bf16)x0.x; w0[1] = (__bf16)x0.y; w0[2] = (__bf16)x0.z; w0[3] = (__bf16)x0.w;
      w0[4] = (__bf16)x1.x; w0[5] = (__bf16)x1.y; w0[6] = (__bf16)x1.z; w0[7] = (__bf16)x1.w;
      w1[0] = (__bf16)x2.x; w1[1] = (__bf16)x2.y; w1[2] = (__bf16)x2.z; w1[3] = (__bf16)x2.w;
      w1[4] = (__bf16)x3.x; w1[5] = (__bf16)x3.y; w1[6] = (__bf16)x3.z; w1[7] = (__bf16)x3.w;
      const int colb = ((c0 + (r >> 3) * 16) & 63) * 2;
      char* rowp = tsh + r * 128;
      *(bf16x8*)(rowp + colb)      = w0;
      *(bf16x8*)(rowp + colb + 16) = w1;
    }
    __syncthreads();
    {
      const int d   = t >> 2;
      const int sc0 = (t & 3) * 16;
      bf16x8 o0, o1;
#pragma unroll
      for (int i = 0; i < 8; ++i) {
        const int s = sc0 + i;
        o0[i] = *(const __bf16*)(tsh + s * 128 + (((d + (s >> 3) * 16) & 63) * 2));
      }
#pragma unroll
      for (int i = 8; i < 16; ++i) {
        const int s = sc0 + i;
        o1[i - 8] = *(const __bf16*)(tsh + s * 128 + (((d + (s >> 3) * 16) & 63) * 2));
      }
      __hip_bfloat16* dst = vtw + ((size_t)(bh * HD + d)) * SSEQ + st * 64 + sc0;
      *(bf16x8*)(dst)     = o0;
      *(bf16x8*)(dst + 8) = o1;
    }
  }
}

// ---- hot kernel: flash attention, 8 waves x 16 q-rows, K in registers ----
__global__ __launch_bounds__(512, 4) void sdpa_fwd(const float* __restrict__ Qg,
                                                   const __hip_bfloat16* __restrict__ Kw,
                                                   const __hip_bfloat16* __restrict__ VTw,
                                                   float* __restrict__ Og) {
  __shared__ char sh[32768];
  char* vbuf = sh;            // [2][8192] V^T tile (swizzled content)
  char* psh  = sh + 16384;    // [8][2048] per-wave P tile

  const int tid  = threadIdx.x;
  const int wv   = tid >> 6;
  const int lane = tid & 63;
  const int g    = lane >> 4;
  const int qc   = lane & 15;

  // XCD-clustered decode: all 16 q-blocks of a head land on one XCD.
  const int bid = blockIdx.x;
  const int xcd = bid & 7;
  const int rest = bid >> 3;
  const int qb  = rest & 15;
  const int bh  = ((rest >> 4) << 3) | xcd;
  const int bb  = bh >> 4;
  const int hh  = bh & 15;

  const size_t rstride = (size_t)BB * EMBED;
  const float* qb_ptr = Qg + (size_t)bb * EMBED + hh * HD;
  float*       ob     = Og + (size_t)bb * EMBED + hh * HD;
  const char*  kwb = (const char*)(Kw + (size_t)bh * SSEQ * HD);
  const char*  vtb = (const char*)(VTw + (size_t)bh * HD * SSEQ);

  const int qrow0 = qb * BQ + wv * 16;

  // V staging (rule #21: linear LDS dest, inverse-swizzled source)
  const int rW = wv * 8 + (lane >> 3);
  const int cW = (lane & 7) ^ (rW & 7);
  const char* vgS = vtb + (size_t)rW * 4096 + cW * 16;  // + T*128
  char* vdS = vbuf + wv * 1024;                         // + B*8192

#define STAGEV(B, T) gload16(vgS + (size_t)(T) * 128, vdS + (B) * 8192)

  // K fragments in registers (A-operand layout), single-buffered:
  // lane (g,qc), sb: K[s = T*64 + sb*16 + qc][d = g*8..g*8+7] and [d+32..]
  bf16x8 kf[8];
#define LOADK(T)                                                              \
  do {                                                                        \
    _Pragma("unroll")                                                         \
    for (int sb = 0; sb < 4; ++sb) {                                          \
      const char* p_ = kwb + (size_t)((T) * 64 + sb * 16 + qc) * 128 + g * 16;\
      kf[sb * 2 + 0] = *(const bf16x8*)(p_);                                  \
      kf[sb * 2 + 1] = *(const bf16x8*)(p_ + 64);                             \
    }                                                                         \
  } while (0)

  // ---- Q fragments (B-operand layout); scale folds 1/8 * log2(e) ----
  constexpr float QSC = 0.125f * 1.4426950408889634f;
  bf16x8 qf[2];
  {
    const float* qr = qb_ptr + (size_t)(qrow0 + qc) * rstride;
#pragma unroll
    for (int f = 0; f < 2; ++f) {
      const float* p = qr + f * 32 + g * 8;
      float4 a = *(const float4*)p;
      float4 c = *(const float4*)(p + 4);
      qf[f][0] = (__bf16)(a.x * QSC); qf[f][1] = (__bf16)(a.y * QSC);
      qf[f][2] = (__bf16)(a.z * QSC); qf[f][3] = (__bf16)(a.w * QSC);
      qf[f][4] = (__bf16)(c.x * QSC); qf[f][5] = (__bf16)(c.y * QSC);
      qf[f][6] = (__bf16)(c.z * QSC); qf[f][7] = (__bf16)(c.w * QSC);
    }
  }

  f32x4 acc[4];
#pragma unroll
  for (int nb = 0; nb < 4; ++nb) { acc[nb][0] = 0.f; acc[nb][1] = 0.f; acc[nb][2] = 0.f; acc[nb][3] = 0.f; }
  float m = -INFINITY;
  float l = 0.f;

  const int sw = (qc & 7) << 4;
  char* pw = psh + wv * 2048;

  // one tile: QK from kf regs; prefetch next K right after; softmax; PV from LDS
#define TILE(OFF, TNEXT, DOLOAD)                                              \
  do {                                                                        \
    const char* vb = vbuf + (OFF);                                            \
    f32x4 st[4];                                                              \
    __builtin_amdgcn_s_setprio(1);                                            \
    _Pragma("unroll")                                                         \
    for (int sb = 0; sb < 4; ++sb) {                                          \
      f32x4 a; a[0] = 0.f; a[1] = 0.f; a[2] = 0.f; a[3] = 0.f;                \
      a = __builtin_amdgcn_mfma_f32_16x16x32_bf16(kf[sb * 2 + 0], qf[0], a, 0, 0, 0); \
      a = __builtin_amdgcn_mfma_f32_16x16x32_bf16(kf[sb * 2 + 1], qf[1], a, 0, 0, 0); \
      st[sb] = a;                                                             \
    }                                                                         \
    __builtin_amdgcn_s_setprio(0);                                            \
    if (DOLOAD) LOADK(TNEXT);  /* K regs free; load hides under softmax+PV */ \
    float mx = fmaxf(fmaxf(fmaxf(st[0][0], st[0][1]), st[0][2]),              \
                     fmaxf(fmaxf(st[0][3], st[1][0]), st[1][1]));             \
    mx = fmaxf(mx, fmaxf(fmaxf(st[1][2], st[1][3]), st[2][0]));               \
    mx = fmaxf(mx, fmaxf(fmaxf(st[2][1], st[2][2]), st[2][3]));               \
    mx = fmaxf(mx, fmaxf(fmaxf(st[3][0], st[3][1]),                           \
                         fmaxf(st[3][2], st[3][3])));                         \
    mx = fmaxf(mx, __shfl_xor(mx, 16));                                       \
    mx = fmaxf(mx, __shfl_xor(mx, 32));                                       \
    if (!__all(mx - m <= 8.0f)) {                                             \
      const float mnew  = fmaxf(m, mx);                                       \
      const float alpha = exp2_fast(m - mnew);                                \
      m = mnew;                                                               \
      l *= alpha;                                                             \
      float ar[4];                                                            \
      _Pragma("unroll")                                                       \
      for (int r2 = 0; r2 < 4; ++r2) ar[r2] = __shfl(alpha, g * 4 + r2);      \
      _Pragma("unroll")                                                       \
      for (int nb = 0; nb < 4; ++nb)                                          \
        _Pragma("unroll")                                                     \
        for (int r2 = 0; r2 < 4; ++r2) acc[nb][r2] *= ar[r2];                 \
    }                                                                         \
    float rs = 0.f;                                                           \
    _Pragma("unroll")                                                         \
    for (int sb = 0; sb < 4; ++sb)                                            \
      _Pragma("unroll")                                                       \
      for (int r2 = 0; r2 < 4; ++r2) {                                        \
        float p = exp2_fast(st[sb][r2] - m);                                  \
        st[sb][r2] = p;                                                       \
        rs += p;                                                              \
      }                                                                       \
    rs += __shfl_xor(rs, 16);                                                 \
    rs += __shfl_xor(rs, 32);                                                 \
    l += rs;                                                                  \
    _Pragma("unroll")                                                         \
    for (int sb = 0; sb < 4; ++sb) {                                          \
      bf16x4 p4;                                                              \
      p4[0] = (__bf16)st[sb][0]; p4[1] = (__bf16)st[sb][1];                   \
      p4[2] = (__bf16)st[sb][2]; p4[3] = (__bf16)st[sb][3];                   \
      *(bf16x4*)(pw + qc * 128 + ((sb * 32 + g * 8) ^ sw)) = p4;              \
    }                                                                         \
    asm volatile("s_waitcnt lgkmcnt(0)" ::: "memory");                        \
    {                                                                         \
      bf16x8 pa0 = *(const bf16x8*)(pw + qc * 128 + ((g * 16)      ^ sw));    \
      bf16x8 pa1 = *(const bf16x8*)(pw + qc * 128 + ((64 + g * 16) ^ sw));    \
      __builtin_amdgcn_s_setprio(1);                                          \
      _Pragma("unroll")                                                       \
      for (int nb = 0; nb < 4; ++nb) {                                        \
        const int vbase = (nb * 16 + qc) * 128;                               \
        bf16x8 v0f = *(const bf16x8*)(vb + vbase + ((g * 16)      ^ sw));     \
        bf16x8 v1f = *(const bf16x8*)(vb + vbase + ((64 + g * 16) ^ sw));     \
        acc[nb] = __builtin_amdgcn_mfma_f32_16x16x32_bf16(pa0, v0f, acc[nb], 0, 0, 0); \
        acc[nb] = __builtin_amdgcn_mfma_f32_16x16x32_bf16(pa1, v1f, acc[nb], 0, 0, 0); \
      }                                                                       \
      __builtin_amdgcn_s_setprio(0);                                          \
    }                                                                         \
  } while (0)

  LOADK(0);
  STAGEV(0, 0);
  __syncthreads();

  for (int t = 0; t < NT; t += 2) {
    if (t + 1 < NT) STAGEV(1, t + 1);
    TILE(0, t + 1, t + 1 < NT);
    __syncthreads();
    if (t + 2 < NT) STAGEV(0, t + 2);
    TILE(8192, t + 2, t + 2 < NT);
    __syncthreads();
  }
#undef STAGEV
#undef LOADK
#undef TILE

  // ---- epilogue: O /= l, store ----
  float linv[4];
#pragma unroll
  for (int r2 = 0; r2 < 4; ++r2) {
    float lr = __shfl(l, g * 4 + r2);
    linv[r2] = 1.0f / lr;
  }
#pragma unroll
  for (int nb = 0; nb < 4; ++nb)
#pragma unroll
    for (int r2 = 0; r2 < 4; ++r2) {
      const int row = qrow0 + g * 4 + r2;
      ob[(size_t)row * rstride + nb * 16 + qc] = acc[nb][r2] * linv[r2];
    }
}

extern "C" void kernel_launch(void* const* d_in, const int* in_sizes, int n_in,
                              void* d_out, int out_size, void* d_ws, size_t ws_size,
                              hipStream_t stream) {
  const float* q = (const float*)d_in[0];
  const float* k = (const float*)d_in[1];
  const float* v = (const float*)d_in[2];
  float* o = (float*)d_out;
  __hip_bfloat16* kw  = (__hip_bfloat16*)d_ws;
  __hip_bfloat16* vtw = kw + KW_ELEMS;

  prep_kv<<<dim3(3072), dim3(256), 0, stream>>>(k, v, kw, vtw);
  sdpa_fwd<<<dim3(512), dim3(512), 0, stream>>>(q, kw, vtw, o);
}